// Round 1
// baseline (2847.853 us; speedup 1.0000x reference)
//
#include <hip/hip_runtime.h>
#include <hip/hip_bf16.h>
#include <math.h>

// Problem constants (CausalSelfAttention, GPT-2 small shape)
#define BATCH 8
#define SEQ   1024
#define NEMBD 768
#define NHEAD 12
#define HDIM  64
#define TC    (3 * NEMBD)   // 2304

// ---------------------------------------------------------------------------
// Tiled fp32 GEMM + bias:  C[M,N] = A[M,K] @ B[K,N] + bias[N]
// BM=BN=64, BK=16, 256 threads, each thread computes a 4x4 microtile.
// M,N,K must be multiples of 64/64/16 (true for all our shapes).
// ---------------------------------------------------------------------------
__global__ __launch_bounds__(256) void gemm_bias_kernel(
    const float* __restrict__ A, const float* __restrict__ B,
    const float* __restrict__ bias, float* __restrict__ C,
    int M, int N, int K)
{
    constexpr int BM = 64, BN = 64, BK = 16;
    __shared__ float As[BK][BM];       // stored k-major (transposed on load)
    __shared__ float Bs[BK][BN];

    const int tid = threadIdx.x;
    const int bm = blockIdx.y * BM;
    const int bn = blockIdx.x * BN;
    const int ty = tid / 16;           // 0..15 -> row group
    const int tx = tid % 16;           // 0..15 -> col group

    // A-tile load mapping: 64 rows x 16 k, float4 along k
    const int arow = tid / 4;          // 0..63
    const int acol = (tid % 4) * 4;    // 0,4,8,12
    // B-tile load mapping: 16 rows x 64 cols, float4 along n
    const int brow = tid / 16;         // 0..15
    const int bcol = (tid % 16) * 4;   // 0..60

    float acc[4][4] = {};

    for (int k0 = 0; k0 < K; k0 += BK) {
        float4 av = *(const float4*)(A + (size_t)(bm + arow) * K + k0 + acol);
        As[acol + 0][arow] = av.x;
        As[acol + 1][arow] = av.y;
        As[acol + 2][arow] = av.z;
        As[acol + 3][arow] = av.w;
        float4 bv = *(const float4*)(B + (size_t)(k0 + brow) * N + bn + bcol);
        *(float4*)&Bs[brow][bcol] = bv;
        __syncthreads();

        #pragma unroll
        for (int k = 0; k < BK; ++k) {
            float4 ra = *(const float4*)&As[k][ty * 4];
            float4 rb = *(const float4*)&Bs[k][tx * 4];
            acc[0][0] += ra.x * rb.x; acc[0][1] += ra.x * rb.y;
            acc[0][2] += ra.x * rb.z; acc[0][3] += ra.x * rb.w;
            acc[1][0] += ra.y * rb.x; acc[1][1] += ra.y * rb.y;
            acc[1][2] += ra.y * rb.z; acc[1][3] += ra.y * rb.w;
            acc[2][0] += ra.z * rb.x; acc[2][1] += ra.z * rb.y;
            acc[2][2] += ra.z * rb.z; acc[2][3] += ra.z * rb.w;
            acc[3][0] += ra.w * rb.x; acc[3][1] += ra.w * rb.y;
            acc[3][2] += ra.w * rb.z; acc[3][3] += ra.w * rb.w;
        }
        __syncthreads();
    }

    #pragma unroll
    for (int i = 0; i < 4; ++i) {
        const int gr = bm + ty * 4 + i;
        const int gc = bn + tx * 4;
        float4 ov;
        ov.x = acc[i][0] + bias[gc + 0];
        ov.y = acc[i][1] + bias[gc + 1];
        ov.z = acc[i][2] + bias[gc + 2];
        ov.w = acc[i][3] + bias[gc + 3];
        *(float4*)(C + (size_t)gr * N + gc) = ov;
    }
}

// ---------------------------------------------------------------------------
// Flash-style causal attention.
// Grid: (SEQ/64, NHEAD, BATCH), block: 64 threads (1 wave).
// Thread t owns query row qt*64+t: q and o accumulator live in registers;
// K/V tiles (64 keys x 64 dims) staged in LDS (stride 68: float4-aligned,
// write bank conflicts broken). Online softmax, per-key rescale.
// Reads q,k,v directly from interleaved qkv[B,T,3C]; writes y in [B,T,C].
// ---------------------------------------------------------------------------
__global__ __launch_bounds__(64) void attn_kernel(
    const float* __restrict__ qkv, float* __restrict__ y)
{
    constexpr int D = HDIM;
    const int t  = threadIdx.x;        // 0..63, query row within tile
    const int qt = blockIdx.x;
    const int h  = blockIdx.y;
    const int b  = blockIdx.z;
    const int qrow = qt * 64 + t;

    const size_t base = (size_t)b * SEQ * TC;
    const float scale = 0.125f;        // 1/sqrt(64)

    float q[D], o[D];
    const float* qp = qkv + base + (size_t)qrow * TC + h * D;
    #pragma unroll
    for (int d = 0; d < D; d += 4) {
        float4 v = *(const float4*)(qp + d);
        q[d + 0] = v.x * scale; q[d + 1] = v.y * scale;
        q[d + 2] = v.z * scale; q[d + 3] = v.w * scale;
        o[d + 0] = 0.f; o[d + 1] = 0.f; o[d + 2] = 0.f; o[d + 3] = 0.f;
    }

    float m = -INFINITY, l = 0.f;

    __shared__ float Ks[64][D + 4];
    __shared__ float Vs[64][D + 4];

    for (int kt = 0; kt <= qt; ++kt) {
        // stage key/value rows kt*64 .. kt*64+63 (thread t loads key row t)
        const float* kp = qkv + base + (size_t)(kt * 64 + t) * TC + NEMBD + h * D;
        const float* vp = kp + NEMBD;
        #pragma unroll
        for (int d = 0; d < D; d += 4) {
            *(float4*)&Ks[t][d] = *(const float4*)(kp + d);
            *(float4*)&Vs[t][d] = *(const float4*)(vp + d);
        }
        __syncthreads();

        const bool diag = (kt == qt);
        #pragma unroll 1
        for (int k = 0; k < 64; ++k) {
            float s = 0.f;
            #pragma unroll
            for (int d = 0; d < D; ++d) s += q[d] * Ks[k][d];
            if (diag && (kt * 64 + k > qrow)) s = -INFINITY;
            const float mnew  = fmaxf(m, s);
            const float alpha = __expf(m - mnew);   // m=-inf first iter -> 0
            const float p     = __expf(s - mnew);   // masked key -> 0
            l = l * alpha + p;
            #pragma unroll
            for (int d = 0; d < D; ++d) o[d] = o[d] * alpha + p * Vs[k][d];
            m = mnew;
        }
        __syncthreads();
    }

    const float inv = 1.f / l;
    float* yp = y + ((size_t)(b * SEQ) + qrow) * NEMBD + h * D;
    #pragma unroll
    for (int d = 0; d < D; d += 4) {
        float4 v;
        v.x = o[d + 0] * inv; v.y = o[d + 1] * inv;
        v.z = o[d + 2] * inv; v.w = o[d + 3] * inv;
        *(float4*)(yp + d) = v;
    }
}

// ---------------------------------------------------------------------------
extern "C" void kernel_launch(void* const* d_in, const int* in_sizes, int n_in,
                              void* d_out, int out_size, void* d_ws, size_t ws_size,
                              hipStream_t stream)
{
    const float* x      = (const float*)d_in[0];   // [B,T,C]
    const float* w_attn = (const float*)d_in[1];   // [C,3C]
    const float* b_attn = (const float*)d_in[2];   // [3C]
    const float* w_proj = (const float*)d_in[3];   // [C,C]
    const float* b_proj = (const float*)d_in[4];   // [C]
    float* out = (float*)d_out;                    // [B,T,C]

    const int M = BATCH * SEQ;                     // 8192
    float* qkv = (float*)d_ws;                     // M * 3C fp32 = 75.5 MB
    float* yb  = qkv + (size_t)M * TC;             // M * C  fp32 = 25.2 MB

    // 1) qkv = x @ w_attn + b_attn   (M=8192, N=2304, K=768)
    dim3 g1(TC / 64, M / 64);
    gemm_bias_kernel<<<g1, 256, 0, stream>>>(x, w_attn, b_attn, qkv, M, TC, NEMBD);

    // 2) causal attention -> yb [B,T,C]
    dim3 g2(SEQ / 64, NHEAD, BATCH);
    attn_kernel<<<g2, 64, 0, stream>>>(qkv, yb);

    // 3) out = yb @ w_proj + b_proj  (M=8192, N=768, K=768)
    dim3 g3(NEMBD / 64, M / 64);
    gemm_bias_kernel<<<g3, 256, 0, stream>>>(yb, w_proj, b_proj, out, M, NEMBD, NEMBD);
}

// Round 2
// 682.640 us; speedup vs baseline: 4.1718x; 4.1718x over previous
//
#include <hip/hip_runtime.h>
#include <hip/hip_bf16.h>
#include <math.h>
#include <type_traits>

// Problem constants (CausalSelfAttention, GPT-2 small shape)
#define BATCH 8
#define SEQ   1024
#define NEMBD 768
#define NHEAD 12
#define HDIM  64
#define TC    (3 * NEMBD)   // 2304

typedef __attribute__((ext_vector_type(4))) float f32x4;
typedef __attribute__((ext_vector_type(8))) short s16x8;   // 8 bf16 in 4 VGPRs

__device__ __forceinline__ unsigned short f2bf(float f) {
    return __builtin_bit_cast(unsigned short, __float2bfloat16(f));
}

// ---------------------------------------------------------------------------
// Tiled fp32 GEMM + bias, templated output type (fp32 or bf16-as-ushort).
// C[M,N] = A[M,K] @ B[K,N] + bias[N].  BM=BN=64, BK=16, 256 thr, 4x4 microtile.
// ---------------------------------------------------------------------------
template <typename OUT_T>
__global__ __launch_bounds__(256) void gemm_bias_kernel(
    const float* __restrict__ A, const float* __restrict__ B,
    const float* __restrict__ bias, OUT_T* __restrict__ C,
    int M, int N, int K)
{
    constexpr int BM = 64, BN = 64, BK = 16;
    __shared__ float As[BK][BM];
    __shared__ float Bs[BK][BN];

    const int tid = threadIdx.x;
    const int bm = blockIdx.y * BM;
    const int bn = blockIdx.x * BN;
    const int ty = tid / 16;
    const int tx = tid % 16;

    const int arow = tid / 4;
    const int acol = (tid % 4) * 4;
    const int brow = tid / 16;
    const int bcol = (tid % 16) * 4;

    float acc[4][4] = {};

    for (int k0 = 0; k0 < K; k0 += BK) {
        float4 av = *(const float4*)(A + (size_t)(bm + arow) * K + k0 + acol);
        As[acol + 0][arow] = av.x;
        As[acol + 1][arow] = av.y;
        As[acol + 2][arow] = av.z;
        As[acol + 3][arow] = av.w;
        float4 bv = *(const float4*)(B + (size_t)(k0 + brow) * N + bn + bcol);
        *(float4*)&Bs[brow][bcol] = bv;
        __syncthreads();

        #pragma unroll
        for (int k = 0; k < BK; ++k) {
            float4 ra = *(const float4*)&As[k][ty * 4];
            float4 rb = *(const float4*)&Bs[k][tx * 4];
            acc[0][0] += ra.x * rb.x; acc[0][1] += ra.x * rb.y;
            acc[0][2] += ra.x * rb.z; acc[0][3] += ra.x * rb.w;
            acc[1][0] += ra.y * rb.x; acc[1][1] += ra.y * rb.y;
            acc[1][2] += ra.y * rb.z; acc[1][3] += ra.y * rb.w;
            acc[2][0] += ra.z * rb.x; acc[2][1] += ra.z * rb.y;
            acc[2][2] += ra.z * rb.z; acc[2][3] += ra.z * rb.w;
            acc[3][0] += ra.w * rb.x; acc[3][1] += ra.w * rb.y;
            acc[3][2] += ra.w * rb.z; acc[3][3] += ra.w * rb.w;
        }
        __syncthreads();
    }

    #pragma unroll
    for (int i = 0; i < 4; ++i) {
        const int gr = bm + ty * 4 + i;
        const int gc = bn + tx * 4;
        float v0 = acc[i][0] + bias[gc + 0];
        float v1 = acc[i][1] + bias[gc + 1];
        float v2 = acc[i][2] + bias[gc + 2];
        float v3 = acc[i][3] + bias[gc + 3];
        if constexpr (std::is_same<OUT_T, unsigned short>::value) {
            ushort4 ov;
            ov.x = f2bf(v0); ov.y = f2bf(v1); ov.z = f2bf(v2); ov.w = f2bf(v3);
            *(ushort4*)(C + (size_t)gr * N + gc) = ov;
        } else {
            float4 ov; ov.x = v0; ov.y = v1; ov.z = v2; ov.w = v3;
            *(float4*)(C + (size_t)gr * N + gc) = ov;
        }
    }
}

// ---------------------------------------------------------------------------
// Flash-style causal attention, bf16 MFMA (16x16x32).
// Grid: (SEQ/64, NHEAD, BATCH), block 256 (4 waves). Wave w owns q-rows
// [qt*64+w*16, +16). Per 64-key tile: K staged [64][72] bf16 LDS, V staged
// TRANSPOSED Vt[64][72] (row=d, col=k) so PV B-fragments are contiguous
// 16B ds_read_b128. P converted C-layout -> A-layout via per-wave LDS
// round-trip. Online softmax on C-layout frags (row=(l>>4)*4+r, col=l&15,
// HW-verified layout), row-reduce = shfl_xor over lane bits 0..3.
// ---------------------------------------------------------------------------
__global__ __launch_bounds__(256) void attn_mfma_kernel(
    const unsigned short* __restrict__ qkv, float* __restrict__ y)
{
    const int qt = blockIdx.x;
    const int h  = blockIdx.y;
    const int b  = blockIdx.z;
    const int tid  = threadIdx.x;
    const int w    = tid >> 6;        // wave 0..3
    const int lane = tid & 63;
    const int lr   = lane & 15;       // A-row / B-col index
    const int lg   = lane >> 4;       // k-group 0..3

    __shared__ __align__(16) unsigned short Ks[64][72];     // [k][d]
    __shared__ __align__(16) unsigned short Vt[64][72];     // [d][k]  (transposed)
    __shared__ __align__(16) unsigned short Ps[4][16][72];  // per-wave P tile [q][k]

    const size_t base = (size_t)b * SEQ * TC;

    // Q A-fragments (row = lr, d = half*32 + lg*8 + j), loaded once
    const unsigned short* qp =
        qkv + base + (size_t)(qt * 64 + w * 16 + lr) * TC + h * HDIM + lg * 8;
    const s16x8 qf0 = *(const s16x8*)qp;
    const s16x8 qf1 = *(const s16x8*)(qp + 32);

    f32x4 acc[4];
    #pragma unroll
    for (int d = 0; d < 4; ++d) acc[d] = (f32x4){0.f, 0.f, 0.f, 0.f};
    float m[4] = {-INFINITY, -INFINITY, -INFINITY, -INFINITY};
    float l[4] = {0.f, 0.f, 0.f, 0.f};

    // staging index maps (256 threads)
    const int sr  = tid >> 2;         // K row 0..63
    const int sdc = (tid & 3) * 16;   // K d-chunk
    const int vrp = tid >> 3;         // V row-pair 0..31
    const int vdc = (tid & 7) * 8;    // V d-chunk

    for (int kt = 0; kt <= qt; ++kt) {
        __syncthreads();   // prior tile fully consumed before overwrite
        {
            // stage K tile [64][64] bf16
            const unsigned short* kp =
                qkv + base + (size_t)(kt * 64 + sr) * TC + NEMBD + h * HDIM + sdc;
            *(s16x8*)&Ks[sr][sdc]     = *(const s16x8*)kp;
            *(s16x8*)&Ks[sr][sdc + 8] = *(const s16x8*)(kp + 8);
            // stage V tile transposed: Vt[d][k], packed pair writes
            const unsigned short* vp =
                qkv + base + (size_t)(kt * 64 + vrp * 2) * TC + 2 * NEMBD + h * HDIM + vdc;
            s16x8 v0 = *(const s16x8*)vp;
            s16x8 v1 = *(const s16x8*)(vp + TC);
            #pragma unroll
            for (int i = 0; i < 8; ++i) {
                unsigned int pk = (unsigned int)(unsigned short)v0[i] |
                                  ((unsigned int)(unsigned short)v1[i] << 16);
                *(unsigned int*)&Vt[vdc + i][vrp * 2] = pk;
            }
        }
        __syncthreads();

        // ---- S = Q K^T (16q x 64k per wave): 8 MFMAs ----
        f32x4 sf[4];
        #pragma unroll
        for (int s = 0; s < 4; ++s) {
            sf[s] = (f32x4){0.f, 0.f, 0.f, 0.f};
            s16x8 b0 = *(const s16x8*)&Ks[s * 16 + lr][lg * 8];
            s16x8 b1 = *(const s16x8*)&Ks[s * 16 + lr][32 + lg * 8];
            sf[s] = __builtin_amdgcn_mfma_f32_16x16x32_bf16(qf0, b0, sf[s], 0, 0, 0);
            sf[s] = __builtin_amdgcn_mfma_f32_16x16x32_bf16(qf1, b1, sf[s], 0, 0, 0);
        }

        // scale + causal mask (C layout: row q = lg*4+r, col k = s*16+lr)
        float sv[4][4];
        #pragma unroll
        for (int s = 0; s < 4; ++s)
            #pragma unroll
            for (int r = 0; r < 4; ++r)
                sv[s][r] = sf[s][r] * 0.125f;
        if (kt == qt) {
            #pragma unroll
            for (int s = 0; s < 4; ++s)
                #pragma unroll
                for (int r = 0; r < 4; ++r)
                    if (s * 16 + lr > w * 16 + lg * 4 + r) sv[s][r] = -INFINITY;
        }

        // ---- online softmax ----
        float mx[4];
        #pragma unroll
        for (int r = 0; r < 4; ++r)
            mx[r] = fmaxf(fmaxf(sv[0][r], sv[1][r]), fmaxf(sv[2][r], sv[3][r]));
        #pragma unroll
        for (int r = 0; r < 4; ++r) {
            mx[r] = fmaxf(mx[r], __shfl_xor(mx[r], 1, 64));
            mx[r] = fmaxf(mx[r], __shfl_xor(mx[r], 2, 64));
            mx[r] = fmaxf(mx[r], __shfl_xor(mx[r], 4, 64));
            mx[r] = fmaxf(mx[r], __shfl_xor(mx[r], 8, 64));
        }
        float al[4], rs[4];
        #pragma unroll
        for (int r = 0; r < 4; ++r) {
            float mnew = fmaxf(m[r], mx[r]);
            al[r] = __expf(m[r] - mnew);   // m=-inf first tile -> 0
            m[r] = mnew;
            rs[r] = 0.f;
        }
        float p[4][4];
        #pragma unroll
        for (int s = 0; s < 4; ++s)
            #pragma unroll
            for (int r = 0; r < 4; ++r) {
                p[s][r] = __expf(sv[s][r] - m[r]);   // masked -> exp(-inf)=0
                rs[r] += p[s][r];
            }
        #pragma unroll
        for (int r = 0; r < 4; ++r) {
            rs[r] += __shfl_xor(rs[r], 1, 64);
            rs[r] += __shfl_xor(rs[r], 2, 64);
            rs[r] += __shfl_xor(rs[r], 4, 64);
            rs[r] += __shfl_xor(rs[r], 8, 64);
            l[r] = l[r] * al[r] + rs[r];
        }
        #pragma unroll
        for (int d = 0; d < 4; ++d)
            #pragma unroll
            for (int r = 0; r < 4; ++r)
                acc[d][r] *= al[r];

        // ---- P: C-layout -> A-layout via per-wave LDS round trip ----
        #pragma unroll
        for (int s = 0; s < 4; ++s)
            #pragma unroll
            for (int r = 0; r < 4; ++r)
                Ps[w][lg * 4 + r][s * 16 + lr] = f2bf(p[s][r]);
        asm volatile("s_waitcnt lgkmcnt(0)" ::: "memory");
        const s16x8 pa0 = *(const s16x8*)&Ps[w][lr][lg * 8];
        const s16x8 pa1 = *(const s16x8*)&Ps[w][lr][32 + lg * 8];

        // ---- O += P V : 8 MFMAs (B-frag = Vt rows, contiguous k) ----
        #pragma unroll
        for (int d = 0; d < 4; ++d) {
            s16x8 vb0 = *(const s16x8*)&Vt[d * 16 + lr][lg * 8];
            s16x8 vb1 = *(const s16x8*)&Vt[d * 16 + lr][32 + lg * 8];
            acc[d] = __builtin_amdgcn_mfma_f32_16x16x32_bf16(pa0, vb0, acc[d], 0, 0, 0);
            acc[d] = __builtin_amdgcn_mfma_f32_16x16x32_bf16(pa1, vb1, acc[d], 0, 0, 0);
        }
    }

    // epilogue: y[row][h*64 + d*16 + lr] = acc[d][r] / l[r]
    #pragma unroll
    for (int r = 0; r < 4; ++r) {
        const float inv = 1.f / l[r];
        const int row = qt * 64 + w * 16 + lg * 4 + r;
        float* yp = y + (size_t)(b * SEQ + row) * NEMBD + h * HDIM;
        #pragma unroll
        for (int d = 0; d < 4; ++d)
            yp[d * 16 + lr] = acc[d][r] * inv;
    }
}

// ---------------------------------------------------------------------------
extern "C" void kernel_launch(void* const* d_in, const int* in_sizes, int n_in,
                              void* d_out, int out_size, void* d_ws, size_t ws_size,
                              hipStream_t stream)
{
    const float* x      = (const float*)d_in[0];
    const float* w_attn = (const float*)d_in[1];
    const float* b_attn = (const float*)d_in[2];
    const float* w_proj = (const float*)d_in[3];
    const float* b_proj = (const float*)d_in[4];
    float* out = (float*)d_out;

    const int M = BATCH * SEQ;                       // 8192
    unsigned short* qkv = (unsigned short*)d_ws;     // [M, 3C] bf16 = 37.75 MB
    float* yb = (float*)((char*)d_ws + (size_t)M * TC * sizeof(unsigned short));

    // 1) qkv(bf16) = x @ w_attn + b_attn   (M=8192, N=2304, K=768)
    dim3 g1(TC / 64, M / 64);
    gemm_bias_kernel<unsigned short><<<g1, 256, 0, stream>>>(x, w_attn, b_attn, qkv, M, TC, NEMBD);

    // 2) causal MFMA attention -> yb [B,T,C] fp32
    dim3 g2(SEQ / 64, NHEAD, BATCH);
    attn_mfma_kernel<<<g2, 256, 0, stream>>>(qkv, yb);

    // 3) out = yb @ w_proj + b_proj  (M=8192, N=768, K=768)
    dim3 g3(NEMBD / 64, M / 64);
    gemm_bias_kernel<float><<<g3, 256, 0, stream>>>(yb, w_proj, b_proj, out, M, NEMBD, NEMBD);
}

// Round 3
// 190.379 us; speedup vs baseline: 14.9588x; 3.5857x over previous
//
#include <hip/hip_runtime.h>
#include <hip/hip_bf16.h>
#include <math.h>
#include <type_traits>

// Problem constants (CausalSelfAttention, GPT-2 small shape)
#define BATCH 8
#define SEQ   1024
#define NEMBD 768
#define NHEAD 12
#define HDIM  64
#define TC    (3 * NEMBD)   // 2304

typedef __attribute__((ext_vector_type(4))) float f32x4;
typedef __attribute__((ext_vector_type(8))) short s16x8;   // 8 bf16 in 4 VGPRs

__device__ __forceinline__ unsigned short f2bf(float f) {
    return __builtin_bit_cast(unsigned short, __float2bfloat16(f));
}

// async global->LDS, 16B per lane (dwordx4). LDS dest: wave-uniform base +
// lane*16 (we pass per-lane ptrs that match exactly that layout).
__device__ __forceinline__ void gload_lds16(const void* g, void* l) {
    __builtin_amdgcn_global_load_lds(
        (const __attribute__((address_space(1))) void*)g,
        (__attribute__((address_space(3))) void*)l, 16, 0, 0);
}

// ---------------------------------------------------------------------------
// cast fp32 -> bf16, 8 elements/thread (n must be multiple of 2048)
// ---------------------------------------------------------------------------
__global__ __launch_bounds__(256) void cast_bf16_kernel(
    const float* __restrict__ in, unsigned short* __restrict__ out, int n)
{
    const int i = (blockIdx.x * 256 + threadIdx.x) * 8;
    float4 a = *(const float4*)(in + i);
    float4 b = *(const float4*)(in + i + 4);
    s16x8 v;
    v[0] = f2bf(a.x); v[1] = f2bf(a.y); v[2] = f2bf(a.z); v[3] = f2bf(a.w);
    v[4] = f2bf(b.x); v[5] = f2bf(b.y); v[6] = f2bf(b.z); v[7] = f2bf(b.w);
    *(s16x8*)(out + i) = v;
}

// ---------------------------------------------------------------------------
// transpose + cast: w[K][N] fp32 -> wT[N][K] bf16. 32x32 LDS tiles.
// ---------------------------------------------------------------------------
__global__ __launch_bounds__(256) void transpose_cast_kernel(
    const float* __restrict__ w, unsigned short* __restrict__ wT, int K, int N)
{
    __shared__ float t[32][33];
    const int tx = threadIdx.x, ty = threadIdx.y;   // block (32,8)
    const int n0 = blockIdx.x * 32, k0 = blockIdx.y * 32;
    #pragma unroll
    for (int i = 0; i < 4; ++i)
        t[ty + i * 8][tx] = w[(size_t)(k0 + ty + i * 8) * N + n0 + tx];
    __syncthreads();
    #pragma unroll
    for (int i = 0; i < 4; ++i)
        wT[(size_t)(n0 + ty + i * 8) * K + k0 + tx] = f2bf(t[tx][ty + i * 8]);
}

// ---------------------------------------------------------------------------
// bf16 MFMA GEMM + bias (m97 structure): C[M,N] = A[M,K] @ Bt[N,K]^T + bias.
// 128x128 tile, BK=32, 256 threads (4 waves, 2x2), wave = 64x64 out (4x4
// frags of 16x16x32). global_load_lds width=16 staging, linear LDS.
// ---------------------------------------------------------------------------
template <typename OUT_T>
__global__ __launch_bounds__(256) void gemm_mfma_kernel(
    const unsigned short* __restrict__ A,   // [M][K] bf16
    const unsigned short* __restrict__ Bt,  // [N][K] bf16 (= B^T)
    const float* __restrict__ bias,         // [N] fp32
    OUT_T* __restrict__ C,                  // [M][N]
    int M, int N, int K)
{
    __shared__ __align__(16) unsigned short As[128 * 32];
    __shared__ __align__(16) unsigned short Bs[128 * 32];

    const int tid  = threadIdx.x;
    const int w    = tid >> 6, lane = tid & 63;
    const int lr   = lane & 15, lg = lane >> 4;
    const int wr   = w >> 1, wc = w & 1;
    const int bm   = blockIdx.y * 128, bn = blockIdx.x * 128;

    // staging maps: issue covers 64 rows x 32 k (2048 elem = 256 thr x 8)
    const int srow = tid >> 2;
    const int sk   = (tid & 3) * 8;
    const unsigned short* Ag = A  + (size_t)(bm + srow) * K + sk;
    const unsigned short* Bg = Bt + (size_t)(bn + srow) * K + sk;
    unsigned short* Al = As + tid * 8;
    unsigned short* Bl = Bs + tid * 8;
    const size_t half = (size_t)64 * K;

    f32x4 acc[4][4];
    #pragma unroll
    for (int m = 0; m < 4; ++m)
        #pragma unroll
        for (int n = 0; n < 4; ++n) acc[m][n] = (f32x4){0.f, 0.f, 0.f, 0.f};

    for (int k0 = 0; k0 < K; k0 += 32) {
        __syncthreads();                    // prior tile consumed
        gload_lds16(Ag + k0,        Al);
        gload_lds16(Ag + k0 + half, Al + 2048);
        gload_lds16(Bg + k0,        Bl);
        gload_lds16(Bg + k0 + half, Bl + 2048);
        __syncthreads();                    // drains vmcnt before reads

        s16x8 af[4], bfr[4];
        #pragma unroll
        for (int m = 0; m < 4; ++m)
            af[m] = *(const s16x8*)&As[(wr * 64 + m * 16 + lr) * 32 + lg * 8];
        #pragma unroll
        for (int n = 0; n < 4; ++n)
            bfr[n] = *(const s16x8*)&Bs[(wc * 64 + n * 16 + lr) * 32 + lg * 8];
        #pragma unroll
        for (int m = 0; m < 4; ++m)
            #pragma unroll
            for (int n = 0; n < 4; ++n)
                acc[m][n] = __builtin_amdgcn_mfma_f32_16x16x32_bf16(
                    af[m], bfr[n], acc[m][n], 0, 0, 0);
    }

    // epilogue: C row = bm+wr*64+m*16+lg*4+r, col = bn+wc*64+n*16+lr
    #pragma unroll
    for (int n = 0; n < 4; ++n) {
        const int col = bn + wc * 64 + n * 16 + lr;
        const float bv = bias[col];
        #pragma unroll
        for (int m = 0; m < 4; ++m) {
            const int row0 = bm + wr * 64 + m * 16 + lg * 4;
            #pragma unroll
            for (int r = 0; r < 4; ++r) {
                const float v = acc[m][n][r] + bv;
                if constexpr (std::is_same<OUT_T, unsigned short>::value)
                    C[(size_t)(row0 + r) * N + col] = f2bf(v);
                else
                    C[(size_t)(row0 + r) * N + col] = v;
            }
        }
    }
}

// ---------------------------------------------------------------------------
// Flash-style causal attention, bf16 MFMA (16x16x32). Output bf16.
// Grid: (SEQ/64, NHEAD, BATCH), block 256 (4 waves), wave w owns 16 q-rows.
// ---------------------------------------------------------------------------
__global__ __launch_bounds__(256) void attn_mfma_kernel(
    const unsigned short* __restrict__ qkv, unsigned short* __restrict__ y)
{
    const int qt = blockIdx.x;
    const int h  = blockIdx.y;
    const int b  = blockIdx.z;
    const int tid  = threadIdx.x;
    const int w    = tid >> 6;
    const int lane = tid & 63;
    const int lr   = lane & 15;
    const int lg   = lane >> 4;

    __shared__ __align__(16) unsigned short Ks[64][72];     // [k][d]
    __shared__ __align__(16) unsigned short Vt[64][72];     // [d][k]
    __shared__ __align__(16) unsigned short Ps[4][16][72];  // per-wave P [q][k]

    const size_t base = (size_t)b * SEQ * TC;

    const unsigned short* qp =
        qkv + base + (size_t)(qt * 64 + w * 16 + lr) * TC + h * HDIM + lg * 8;
    const s16x8 qf0 = *(const s16x8*)qp;
    const s16x8 qf1 = *(const s16x8*)(qp + 32);

    f32x4 acc[4];
    #pragma unroll
    for (int d = 0; d < 4; ++d) acc[d] = (f32x4){0.f, 0.f, 0.f, 0.f};
    float m[4] = {-INFINITY, -INFINITY, -INFINITY, -INFINITY};
    float l[4] = {0.f, 0.f, 0.f, 0.f};

    const int sr  = tid >> 2;
    const int sdc = (tid & 3) * 16;
    const int vrp = tid >> 3;
    const int vdc = (tid & 7) * 8;

    for (int kt = 0; kt <= qt; ++kt) {
        __syncthreads();
        {
            const unsigned short* kp =
                qkv + base + (size_t)(kt * 64 + sr) * TC + NEMBD + h * HDIM + sdc;
            *(s16x8*)&Ks[sr][sdc]     = *(const s16x8*)kp;
            *(s16x8*)&Ks[sr][sdc + 8] = *(const s16x8*)(kp + 8);
            const unsigned short* vp =
                qkv + base + (size_t)(kt * 64 + vrp * 2) * TC + 2 * NEMBD + h * HDIM + vdc;
            s16x8 v0 = *(const s16x8*)vp;
            s16x8 v1 = *(const s16x8*)(vp + TC);
            #pragma unroll
            for (int i = 0; i < 8; ++i) {
                unsigned int pk = (unsigned int)(unsigned short)v0[i] |
                                  ((unsigned int)(unsigned short)v1[i] << 16);
                *(unsigned int*)&Vt[vdc + i][vrp * 2] = pk;
            }
        }
        __syncthreads();

        // S = Q K^T
        f32x4 sf[4];
        #pragma unroll
        for (int s = 0; s < 4; ++s) {
            sf[s] = (f32x4){0.f, 0.f, 0.f, 0.f};
            s16x8 b0 = *(const s16x8*)&Ks[s * 16 + lr][lg * 8];
            s16x8 b1 = *(const s16x8*)&Ks[s * 16 + lr][32 + lg * 8];
            sf[s] = __builtin_amdgcn_mfma_f32_16x16x32_bf16(qf0, b0, sf[s], 0, 0, 0);
            sf[s] = __builtin_amdgcn_mfma_f32_16x16x32_bf16(qf1, b1, sf[s], 0, 0, 0);
        }

        float sv[4][4];
        #pragma unroll
        for (int s = 0; s < 4; ++s)
            #pragma unroll
            for (int r = 0; r < 4; ++r)
                sv[s][r] = sf[s][r] * 0.125f;
        if (kt == qt) {
            #pragma unroll
            for (int s = 0; s < 4; ++s)
                #pragma unroll
                for (int r = 0; r < 4; ++r)
                    if (s * 16 + lr > w * 16 + lg * 4 + r) sv[s][r] = -INFINITY;
        }

        // online softmax
        float mx[4];
        #pragma unroll
        for (int r = 0; r < 4; ++r)
            mx[r] = fmaxf(fmaxf(sv[0][r], sv[1][r]), fmaxf(sv[2][r], sv[3][r]));
        #pragma unroll
        for (int r = 0; r < 4; ++r) {
            mx[r] = fmaxf(mx[r], __shfl_xor(mx[r], 1, 64));
            mx[r] = fmaxf(mx[r], __shfl_xor(mx[r], 2, 64));
            mx[r] = fmaxf(mx[r], __shfl_xor(mx[r], 4, 64));
            mx[r] = fmaxf(mx[r], __shfl_xor(mx[r], 8, 64));
        }
        float al[4], rs[4];
        #pragma unroll
        for (int r = 0; r < 4; ++r) {
            float mnew = fmaxf(m[r], mx[r]);
            al[r] = __expf(m[r] - mnew);
            m[r] = mnew;
            rs[r] = 0.f;
        }
        float p[4][4];
        #pragma unroll
        for (int s = 0; s < 4; ++s)
            #pragma unroll
            for (int r = 0; r < 4; ++r) {
                p[s][r] = __expf(sv[s][r] - m[r]);
                rs[r] += p[s][r];
            }
        #pragma unroll
        for (int r = 0; r < 4; ++r) {
            rs[r] += __shfl_xor(rs[r], 1, 64);
            rs[r] += __shfl_xor(rs[r], 2, 64);
            rs[r] += __shfl_xor(rs[r], 4, 64);
            rs[r] += __shfl_xor(rs[r], 8, 64);
            l[r] = l[r] * al[r] + rs[r];
        }
        #pragma unroll
        for (int d = 0; d < 4; ++d)
            #pragma unroll
            for (int r = 0; r < 4; ++r)
                acc[d][r] *= al[r];

        // P: C-layout -> A-layout via per-wave LDS round trip
        #pragma unroll
        for (int s = 0; s < 4; ++s)
            #pragma unroll
            for (int r = 0; r < 4; ++r)
                Ps[w][lg * 4 + r][s * 16 + lr] = f2bf(p[s][r]);
        asm volatile("s_waitcnt lgkmcnt(0)" ::: "memory");
        __builtin_amdgcn_sched_barrier(0);
        const s16x8 pa0 = *(const s16x8*)&Ps[w][lr][lg * 8];
        const s16x8 pa1 = *(const s16x8*)&Ps[w][lr][32 + lg * 8];

        // O += P V
        #pragma unroll
        for (int d = 0; d < 4; ++d) {
            s16x8 vb0 = *(const s16x8*)&Vt[d * 16 + lr][lg * 8];
            s16x8 vb1 = *(const s16x8*)&Vt[d * 16 + lr][32 + lg * 8];
            acc[d] = __builtin_amdgcn_mfma_f32_16x16x32_bf16(pa0, vb0, acc[d], 0, 0, 0);
            acc[d] = __builtin_amdgcn_mfma_f32_16x16x32_bf16(pa1, vb1, acc[d], 0, 0, 0);
        }
    }

    // epilogue -> bf16 y
    #pragma unroll
    for (int r = 0; r < 4; ++r) {
        const float inv = 1.f / l[r];
        const int row = qt * 64 + w * 16 + lg * 4 + r;
        unsigned short* yp = y + (size_t)(b * SEQ + row) * NEMBD + h * HDIM;
        #pragma unroll
        for (int d = 0; d < 4; ++d)
            yp[d * 16 + lr] = f2bf(acc[d][r] * inv);
    }
}

// ---------------------------------------------------------------------------
extern "C" void kernel_launch(void* const* d_in, const int* in_sizes, int n_in,
                              void* d_out, int out_size, void* d_ws, size_t ws_size,
                              hipStream_t stream)
{
    const float* x      = (const float*)d_in[0];
    const float* w_attn = (const float*)d_in[1];
    const float* b_attn = (const float*)d_in[2];
    const float* w_proj = (const float*)d_in[3];
    const float* b_proj = (const float*)d_in[4];
    float* out = (float*)d_out;

    const int M = BATCH * SEQ;                       // 8192

    // workspace layout (bf16 buffers)
    char* ws = (char*)d_ws;
    unsigned short* qkv = (unsigned short*)ws;                         // [M][2304]
    unsigned short* yb  = (unsigned short*)(ws + (size_t)M * TC * 2);  // [M][768]
    unsigned short* xb  = (unsigned short*)(ws + (size_t)M * TC * 2
                                               + (size_t)M * NEMBD * 2);
    unsigned short* waT = xb + (size_t)M * NEMBD;                      // [2304][768]
    unsigned short* wpT = waT + (size_t)TC * NEMBD;                    // [768][768]

    // 0) casts / transposes (bf16 prep)
    cast_bf16_kernel<<<(M * NEMBD) / 2048, 256, 0, stream>>>(x, xb, M * NEMBD);
    transpose_cast_kernel<<<dim3(TC / 32, NEMBD / 32), dim3(32, 8), 0, stream>>>(
        w_attn, waT, NEMBD, TC);
    transpose_cast_kernel<<<dim3(NEMBD / 32, NEMBD / 32), dim3(32, 8), 0, stream>>>(
        w_proj, wpT, NEMBD, NEMBD);

    // 1) qkv(bf16) = xb @ waT^T + b_attn   (M=8192, N=2304, K=768)
    gemm_mfma_kernel<unsigned short><<<dim3(TC / 128, M / 128), 256, 0, stream>>>(
        xb, waT, b_attn, qkv, M, TC, NEMBD);

    // 2) causal MFMA attention -> yb bf16 [B,T,C]
    attn_mfma_kernel<<<dim3(SEQ / 64, NHEAD, BATCH), 256, 0, stream>>>(qkv, yb);

    // 3) out(fp32) = yb @ wpT^T + b_proj   (M=8192, N=768, K=768)
    gemm_mfma_kernel<float><<<dim3(NEMBD / 128, M / 128), 256, 0, stream>>>(
        yb, wpT, b_proj, out, M, NEMBD, NEMBD);
}